// Round 7
// baseline (131.941 us; speedup 1.0000x reference)
//
#include <hip/hip_runtime.h>
#include <cstdint>
#include <cstddef>

// ContrastiveLoss: B=8192, D=256 fp32 inputs.
// loss = mean_b [ log( exp(pos_b*2) + sum_c exp(2*z_i[b].z_k[c]) ) - pos_b*2 ]
// R6: R4 ring structure (best known) + occupancy fix:
//   NT=4 -> grid 1024 blocks = 4 blocks/CU (was 2), __launch_bounds__(256,4).
//   A persistent in registers (af[8][4], loaded once, L2-hot); B streamed
//   through a 4-deep LDS ring, stage depth 2, vmcnt(4), one barrier per step.
// exp fused per tile; shuffle-reduce + atomics once per block.

constexpr int   D_DIM = 256;
constexpr float INV_T = 2.0f;   // 1/T, T=0.5

constexpr int BM = 128;
constexpr int BN = 128;
constexpr int BK = 32;
constexpr int NT = 4;           // column tiles per block (each 128 cols)

typedef __attribute__((ext_vector_type(8))) short  bf16x8;
typedef __attribute__((ext_vector_type(4))) float  f32x4;

__device__ __forceinline__ unsigned short f32_to_bf16(float f) {
    unsigned int u = __float_as_uint(f);
    u += 0x7FFFu + ((u >> 16) & 1u);          // RNE
    return (unsigned short)(u >> 16);
}

__device__ __forceinline__ void gload_lds16(const void* g, void* l) {
    auto gp = reinterpret_cast<const __attribute__((address_space(1))) unsigned int*>(
        reinterpret_cast<uintptr_t>(g));
    auto lp = reinterpret_cast<__attribute__((address_space(3))) unsigned int*>(
        reinterpret_cast<uintptr_t>(l));
    __builtin_amdgcn_global_load_lds(gp, lp, 16, 0, 0);
}

// ---------------------------------------------------------------------------
// Kernel 1: per-row norms; write normalized bf16 z_i, z_k; fp32 pos_logit.
// Also zero-initializes rowsum.
// ---------------------------------------------------------------------------
__global__ __launch_bounds__(256) void prep_kernel(
    const float* __restrict__ ei, const float* __restrict__ ej,
    const float* __restrict__ ek,
    unsigned short* __restrict__ zi, unsigned short* __restrict__ zk,
    float* __restrict__ pos_logit, float* __restrict__ rowsum, int B)
{
    const int w    = (int)((blockIdx.x * blockDim.x + threadIdx.x) >> 6);
    const int lane = (int)(threadIdx.x & 63);
    if (w >= B) return;

    const float4 vi = ((const float4*)(ei + (size_t)w * D_DIM))[lane];
    const float4 vj = ((const float4*)(ej + (size_t)w * D_DIM))[lane];
    const float4 vk = ((const float4*)(ek + (size_t)w * D_DIM))[lane];

    float ssi = vi.x*vi.x + vi.y*vi.y + vi.z*vi.z + vi.w*vi.w;
    float ssj = vj.x*vj.x + vj.y*vj.y + vj.z*vj.z + vj.w*vj.w;
    float ssk = vk.x*vk.x + vk.y*vk.y + vk.z*vk.z + vk.w*vk.w;
    float dij = vi.x*vj.x + vi.y*vj.y + vi.z*vj.z + vi.w*vj.w;

    #pragma unroll
    for (int off = 32; off; off >>= 1) {
        ssi += __shfl_xor(ssi, off);
        ssj += __shfl_xor(ssj, off);
        ssk += __shfl_xor(ssk, off);
        dij += __shfl_xor(dij, off);
    }
    const float ri = 1.0f / fmaxf(sqrtf(ssi), 1e-12f);
    const float rj = 1.0f / fmaxf(sqrtf(ssj), 1e-12f);
    const float rk = 1.0f / fmaxf(sqrtf(ssk), 1e-12f);

    ushort4 oi, ok;
    oi.x = f32_to_bf16(vi.x * ri); oi.y = f32_to_bf16(vi.y * ri);
    oi.z = f32_to_bf16(vi.z * ri); oi.w = f32_to_bf16(vi.w * ri);
    ok.x = f32_to_bf16(vk.x * rk); ok.y = f32_to_bf16(vk.y * rk);
    ok.z = f32_to_bf16(vk.z * rk); ok.w = f32_to_bf16(vk.w * rk);
    ((ushort4*)(zi + (size_t)w * D_DIM))[lane] = oi;
    ((ushort4*)(zk + (size_t)w * D_DIM))[lane] = ok;

    if (lane == 0) {
        pos_logit[w] = dij * ri * rj * INV_T;
        rowsum[w]    = 0.0f;
    }
}

// ---------------------------------------------------------------------------
// Kernel 2: rows [by*128,+128) x cols [bx*512,+512) of C = Z_i . Z_k^T.
// A panel in REGISTERS (af[8][4] per wave, loaded once from global);
// B streamed over 32 K-steps through a 4-deep LDS ring, stage depth 2,
// vmcnt(4), one s_barrier per step. 4 waves (2x2), wave tile 64x64 =
// 4x4 frags of 16x16x32 bf16 MFMA.
// B swizzle (verified: conflicts=0): LDS[row][c] = global[row][c ^ swz(row)]
// via pre-swizzled global source (linear LDS dest, rule 21).
// ---------------------------------------------------------------------------
__global__ __launch_bounds__(256, 4) void sim_mfma_kernel(
    const unsigned short* __restrict__ zi, const unsigned short* __restrict__ zk,
    float* __restrict__ rowsum)
{
    __shared__ unsigned short Bs[4][BN * BK];      // 4 x 8 KB ring

    const int t  = (int)threadIdx.x;
    const int w  = t >> 6;        // wave 0..3
    const int l  = t & 63;
    const int wr = w >> 1;        // wave row (0..1)
    const int wc = w & 1;         // wave col (0..1)
    const int rowBase = (int)blockIdx.y * BM;
    const int colBase = (int)blockIdx.x * (NT * BN);

    // ---- A fragments -> registers (once). Frag (kt,mi): lane l holds
    // row rowBase+wr*64+mi*16+(l&15), k elems kt*32+(l>>4)*8 .. +8.
    const int rA = l & 15;
    const int ks = (l >> 4) * 8;
    bf16x8 af[8][4];
    #pragma unroll
    for (int mi = 0; mi < 4; ++mi) {
        const unsigned short* rowp =
            zi + (size_t)(rowBase + wr * 64 + mi * 16 + rA) * D_DIM + ks;
        #pragma unroll
        for (int kt = 0; kt < 8; ++kt)
            af[kt][mi] = *(const bf16x8*)(rowp + kt * BK);
    }

    // ---- B staging addresses (per-lane constants) ----
    // wave w, instr q in {0,1}: rows [w*32+q*16,+16); lane l -> row +(l>>2),
    // 16B unit (l&3); source col pre-swizzled (elems).
    const int csrc = 8 * ((l & 3) ^ ((l >> 3) & 3));
    const unsigned short* gB0 =
        zk + (size_t)(colBase + w * 32 + (l >> 2)) * D_DIM + csrc;
    const int bQ0 = w * 1024;          // LDS element base (wave-uniform)
    const int bQ1 = bQ0 + 512;

    // stage B for global K-step s (s = tile*8 + kt) into ring slot
    #define STAGEB(slot, s) {                                                \
        const unsigned short* src = gB0                                      \
            + (size_t)((s) >> 3) * (BN * D_DIM) + (size_t)((s) & 7) * BK;    \
        gload_lds16(src,              &Bs[slot][bQ0]);                       \
        gload_lds16(src + 16 * D_DIM, &Bs[slot][bQ1]);                       \
    }

    STAGEB(0, 0);
    STAGEB(1, 1);

    // B fragment read offset (swizzled k-col, elems)
    const int ce = 8 * ((l >> 4) ^ ((rA >> 1) & 3));

    float partAcc[4][4] = {};    // per-(mi,reg) running exp-sums across tiles

    for (int nt = 0; nt < NT; ++nt) {
        f32x4 acc[4][4] = {};

        #pragma unroll
        for (int kt = 0; kt < 8; ++kt) {
            // slot arithmetic: s = nt*8+kt, nt*8 % 4 == 0 -> slots are
            // compile-time (kt&3 read, (kt+2)&3 stage).
            int s2 = nt * 8 + kt + 2;
            if (s2 > NT * 8 - 1) s2 = NT * 8 - 1;  // junk restage at tail: ok
            STAGEB((kt + 2) & 3, s2);
            asm volatile("s_waitcnt vmcnt(4)" ::: "memory");  // B(s) landed
            __builtin_amdgcn_s_barrier();
            asm volatile("" ::: "memory");

            bf16x8 bfr[4];
            #pragma unroll
            for (int ni = 0; ni < 4; ++ni)
                bfr[ni] = *(const bf16x8*)
                    &Bs[kt & 3][(wc * 64 + ni * 16 + rA) * BK + ce];

            #pragma unroll
            for (int mi = 0; mi < 4; ++mi)
                #pragma unroll
                for (int ni = 0; ni < 4; ++ni)
                    acc[mi][ni] = __builtin_amdgcn_mfma_f32_16x16x32_bf16(
                        af[kt][mi], bfr[ni], acc[mi][ni], 0, 0, 0);
        }

        // per-tile epilogue: exp + in-lane partial sums (no shuffles here)
        #pragma unroll
        for (int mi = 0; mi < 4; ++mi)
            #pragma unroll
            for (int r = 0; r < 4; ++r) {
                float s = 0.f;
                #pragma unroll
                for (int ni = 0; ni < 4; ++ni)
                    s += __expf(INV_T * acc[mi][ni][r]);
                partAcc[mi][r] += s;
            }
    }
    #undef STAGEB

    // block epilogue: reduce across the 16 column-lanes, one atomic set
    #pragma unroll
    for (int off = 1; off <= 8; off <<= 1)
        #pragma unroll
        for (int mi = 0; mi < 4; ++mi)
            #pragma unroll
            for (int r = 0; r < 4; ++r)
                partAcc[mi][r] += __shfl_xor(partAcc[mi][r], off);

    if ((l & 15) == 0) {
        const int rg = (l >> 4) * 4;     // C/D layout: row = (l>>4)*4 + reg
        #pragma unroll
        for (int mi = 0; mi < 4; ++mi)
            #pragma unroll
            for (int r = 0; r < 4; ++r)
                atomicAdd(&rowsum[rowBase + wr * 64 + mi * 16 + rg + r],
                          partAcc[mi][r]);
    }
}

// ---------------------------------------------------------------------------
// Kernel 3: loss = mean_b [ log(exp(pos_b) + rowsum_b) - pos_b ]
// ---------------------------------------------------------------------------
__global__ __launch_bounds__(1024) void finalize_kernel(
    const float* __restrict__ pos_logit, const float* __restrict__ rowsum,
    float* __restrict__ out, int B)
{
    __shared__ float red[1024];
    float acc = 0.f;
    for (int b = (int)threadIdx.x; b < B; b += 1024) {
        const float pl = pos_logit[b];
        acc += logf(expf(pl) + rowsum[b]) - pl;
    }
    red[threadIdx.x] = acc;
    __syncthreads();
    #pragma unroll
    for (int s = 512; s; s >>= 1) {
        if ((int)threadIdx.x < s) red[threadIdx.x] += red[threadIdx.x + s];
        __syncthreads();
    }
    if (threadIdx.x == 0) out[0] = red[0] / (float)B;
}

// ---------------------------------------------------------------------------
extern "C" void kernel_launch(void* const* d_in, const int* in_sizes, int n_in,
                              void* d_out, int out_size, void* d_ws, size_t ws_size,
                              hipStream_t stream)
{
    const float* ei = (const float*)d_in[0];
    const float* ej = (const float*)d_in[1];
    const float* ek = (const float*)d_in[2];
    const int B = in_sizes[0] / D_DIM;   // 8192

    unsigned short* zi = (unsigned short*)d_ws;
    unsigned short* zk = zi + (size_t)B * D_DIM;
    float* rowsum      = (float*)(zk + (size_t)B * D_DIM);
    float* pos_logit   = rowsum + B;

    prep_kernel<<<dim3((B + 3) / 4), dim3(256), 0, stream>>>(
        ei, ej, ek, zi, zk, pos_logit, rowsum, B);

    dim3 grid(B / (NT * BN), B / BM);    // (16, 64) = 1024 blocks = 4/CU
    sim_mfma_kernel<<<grid, dim3(256), 0, stream>>>(zi, zk, rowsum);

    finalize_kernel<<<dim3(1), dim3(1024), 0, stream>>>(
        pos_logit, rowsum, (float*)d_out, B);
}

// Round 8
// 55.238 us; speedup vs baseline: 2.3886x; 2.3886x over previous
//
#include <hip/hip_runtime.h>
#include <cstdint>
#include <cstddef>

// ContrastiveLoss: B=8192, D=256 fp32 inputs.
// loss = mean_b [ log( exp(2*pos_b) + sum_c exp(2*z_i[b].z_k[c]) ) - 2*pos_b ]
// R7: A persistent in registers (af[8][4]); B staged in HALF-TILE batches:
// dbuf 2 x 32 KB (128 cols x 128 k), ONE vmcnt(8) + one barrier-pair per
// 4 K-steps (64 MFMAs/wave). z_i pre-scaled by 2 so epilogue is exp(acc).
// 2 blocks/CU (register-bound: af+acc ~240 regs/wave on unified file).

constexpr int   D_DIM = 256;
constexpr float INV_T = 2.0f;   // 1/T, T=0.5

constexpr int BM = 128;
constexpr int BN = 128;
constexpr int NT = 8;           // column tiles per block (each 128 cols)

typedef __attribute__((ext_vector_type(8))) short  bf16x8;
typedef __attribute__((ext_vector_type(4))) float  f32x4;

__device__ __forceinline__ unsigned short f32_to_bf16(float f) {
    unsigned int u = __float_as_uint(f);
    u += 0x7FFFu + ((u >> 16) & 1u);          // RNE
    return (unsigned short)(u >> 16);
}

__device__ __forceinline__ void gload_lds16(const void* g, void* l) {
    auto gp = reinterpret_cast<const __attribute__((address_space(1))) unsigned int*>(
        reinterpret_cast<uintptr_t>(g));
    auto lp = reinterpret_cast<__attribute__((address_space(3))) unsigned int*>(
        reinterpret_cast<uintptr_t>(l));
    __builtin_amdgcn_global_load_lds(gp, lp, 16, 0, 0);
}

// ---------------------------------------------------------------------------
// Kernel 1: per-row norms; write bf16 2*z_i (scaled!) and z_k; fp32 pos_logit.
// Also zero-initializes rowsum.
// ---------------------------------------------------------------------------
__global__ __launch_bounds__(256) void prep_kernel(
    const float* __restrict__ ei, const float* __restrict__ ej,
    const float* __restrict__ ek,
    unsigned short* __restrict__ zi, unsigned short* __restrict__ zk,
    float* __restrict__ pos_logit, float* __restrict__ rowsum, int B)
{
    const int w    = (int)((blockIdx.x * blockDim.x + threadIdx.x) >> 6);
    const int lane = (int)(threadIdx.x & 63);
    if (w >= B) return;

    const float4 vi = ((const float4*)(ei + (size_t)w * D_DIM))[lane];
    const float4 vj = ((const float4*)(ej + (size_t)w * D_DIM))[lane];
    const float4 vk = ((const float4*)(ek + (size_t)w * D_DIM))[lane];

    float ssi = vi.x*vi.x + vi.y*vi.y + vi.z*vi.z + vi.w*vi.w;
    float ssj = vj.x*vj.x + vj.y*vj.y + vj.z*vj.z + vj.w*vj.w;
    float ssk = vk.x*vk.x + vk.y*vk.y + vk.z*vk.z + vk.w*vk.w;
    float dij = vi.x*vj.x + vi.y*vj.y + vi.z*vj.z + vi.w*vj.w;

    #pragma unroll
    for (int off = 32; off; off >>= 1) {
        ssi += __shfl_xor(ssi, off);
        ssj += __shfl_xor(ssj, off);
        ssk += __shfl_xor(ssk, off);
        dij += __shfl_xor(dij, off);
    }
    const float ri = INV_T / fmaxf(sqrtf(ssi), 1e-12f);   // fold 1/T into z_i
    const float rj = 1.0f  / fmaxf(sqrtf(ssj), 1e-12f);
    const float rk = 1.0f  / fmaxf(sqrtf(ssk), 1e-12f);

    ushort4 oi, ok;
    oi.x = f32_to_bf16(vi.x * ri); oi.y = f32_to_bf16(vi.y * ri);
    oi.z = f32_to_bf16(vi.z * ri); oi.w = f32_to_bf16(vi.w * ri);
    ok.x = f32_to_bf16(vk.x * rk); ok.y = f32_to_bf16(vk.y * rk);
    ok.z = f32_to_bf16(vk.z * rk); ok.w = f32_to_bf16(vk.w * rk);
    ((ushort4*)(zi + (size_t)w * D_DIM))[lane] = oi;
    ((ushort4*)(zk + (size_t)w * D_DIM))[lane] = ok;

    if (lane == 0) {
        // pos_logit from fp32 (ri already includes 1/T)
        pos_logit[w] = dij * ri * rj;
        rowsum[w]    = 0.0f;
    }
}

// ---------------------------------------------------------------------------
// Kernel 2: rows [by*128,+128) x cols [bx*1024,+1024) of exp-sum of
// (2*Z_i) . Z_k^T. A in registers; B in half-tile dbuf (2 x 32 KB):
// half h (= tile*2 + khalf) covers cols [tile*128,+128) x k [khalf*128,+128),
// stored as 4 k-subtiles p of [128 rows][32 k] (verified swizzled layout).
// Per half: stage next half (8 DMA/wave), vmcnt(8), barrier, 4 K-steps x
// (4 ds_read + 16 MFMA), barrier. 4 waves (2x2), wave tile 64x64.
// ---------------------------------------------------------------------------
__global__ __launch_bounds__(256, 2) void sim_mfma_kernel(
    const unsigned short* __restrict__ zi, const unsigned short* __restrict__ zk,
    float* __restrict__ rowsum)
{
    __shared__ unsigned short Bs[2][4][BN * 32];   // 2 slots x 4 subtiles x 8KB

    const int t  = (int)threadIdx.x;
    const int w  = t >> 6;        // wave 0..3
    const int l  = t & 63;
    const int wr = w >> 1;        // wave row (0..1)
    const int wc = w & 1;         // wave col (0..1)
    const int rowBase = (int)blockIdx.y * BM;
    const int colBase = (int)blockIdx.x * (NT * BN);

    // ---- A fragments -> registers (once). Frag (kt,mi): lane l holds
    // row rowBase+wr*64+mi*16+(l&15), k elems kt*32+(l>>4)*8 .. +8.
    const int rA = l & 15;
    const int ks = (l >> 4) * 8;
    bf16x8 af[8][4];
    #pragma unroll
    for (int mi = 0; mi < 4; ++mi) {
        const unsigned short* rowp =
            zi + (size_t)(rowBase + wr * 64 + mi * 16 + rA) * D_DIM + ks;
        #pragma unroll
        for (int kt = 0; kt < 8; ++kt)
            af[kt][mi] = *(const bf16x8*)(rowp + kt * 32);
    }

    // ---- B staging (per-lane constants) ----
    // wave w, q in {0,1}, p in {0..3}: subtile p, rows [w*32+q*16,+16);
    // lane l -> row +(l>>2), 16B unit (l&3); source col pre-swizzled.
    const int csrc = 8 * ((l & 3) ^ ((l >> 3) & 3));
    const unsigned short* gBw =
        zk + (size_t)(colBase + w * 32 + (l >> 2)) * D_DIM + csrc;
    const int bQ = w * 1024;           // elem base within a subtile (uniform)

    // stage half h (h = tile*2 + khalf) into slot: 8 DMA per wave
    #define STAGEH(slot, h) {                                                 \
        const unsigned short* hb = gBw                                        \
            + (size_t)((h) >> 1) * (BN * D_DIM) + ((h) & 1) * 128;            \
        _Pragma("unroll")                                                     \
        for (int p = 0; p < 4; ++p) {                                         \
            gload_lds16(hb + p * 32,                &Bs[slot][p][bQ]);        \
            gload_lds16(hb + p * 32 + 16 * D_DIM,   &Bs[slot][p][bQ + 512]);  \
        }                                                                     \
    }

    // B fragment read offset (swizzled k-col within [row][32] subtile)
    const int ce = 8 * ((l >> 4) ^ ((rA >> 1) & 3));
    #define BFRAG(slot, p, ni) \
        (*(const bf16x8*)&Bs[slot][p][(wc * 64 + (ni) * 16 + rA) * 32 + ce])

    // one half-step of compute: steps p=0..3 use af[base+p]
    #define COMPUTE_HALF(slot, kbase)                                         \
        _Pragma("unroll")                                                     \
        for (int p = 0; p < 4; ++p) {                                         \
            bf16x8 bfr[4];                                                    \
            _Pragma("unroll")                                                 \
            for (int ni = 0; ni < 4; ++ni) bfr[ni] = BFRAG(slot, p, ni);      \
            __builtin_amdgcn_s_setprio(1);                                    \
            _Pragma("unroll")                                                 \
            for (int mi = 0; mi < 4; ++mi)                                    \
                _Pragma("unroll")                                             \
                for (int ni = 0; ni < 4; ++ni)                                \
                    acc[mi][ni] = __builtin_amdgcn_mfma_f32_16x16x32_bf16(    \
                        af[(kbase) + p][mi], bfr[ni], acc[mi][ni], 0, 0, 0);  \
            __builtin_amdgcn_s_setprio(0);                                    \
        }

    STAGEH(0, 0);                      // prologue: half 0 -> slot 0

    float partAcc[4][4] = {};    // per-(mi,reg) running exp-sums across tiles

    for (int nt = 0; nt < NT; ++nt) {
        f32x4 acc[4][4] = {};

        // ---- half 0 of tile nt (h = 2nt, slot 0) ----
        {
            const int h1 = 2 * nt + 1;            // always <= 15
            STAGEH(1, h1);
            asm volatile("s_waitcnt vmcnt(8)" ::: "memory");  // half 2nt in
            __builtin_amdgcn_s_barrier();
            asm volatile("" ::: "memory");
            COMPUTE_HALF(0, 0);
            asm volatile("" ::: "memory");
            __builtin_amdgcn_s_barrier();         // slot 0 free to restage
            asm volatile("" ::: "memory");
        }
        // ---- half 1 of tile nt (h = 2nt+1, slot 1) ----
        {
            int h2 = 2 * nt + 2;
            if (h2 > 15) h2 = 15;                 // junk data into slot 0 (unread)
            STAGEH(0, h2);
            asm volatile("s_waitcnt vmcnt(8)" ::: "memory");  // half 2nt+1 in
            __builtin_amdgcn_s_barrier();
            asm volatile("" ::: "memory");
            COMPUTE_HALF(1, 4);
            asm volatile("" ::: "memory");
            __builtin_amdgcn_s_barrier();         // slot 1 free to restage
            asm volatile("" ::: "memory");
        }

        // per-tile epilogue: exp + in-lane partial sums (A pre-scaled by 2)
        #pragma unroll
        for (int mi = 0; mi < 4; ++mi)
            #pragma unroll
            for (int r = 0; r < 4; ++r) {
                float s = 0.f;
                #pragma unroll
                for (int ni = 0; ni < 4; ++ni)
                    s += __expf(acc[mi][ni][r]);
                partAcc[mi][r] += s;
            }
    }
    #undef STAGEH
    #undef BFRAG
    #undef COMPUTE_HALF

    // block epilogue: reduce across the 16 column-lanes, one atomic set
    #pragma unroll
    for (int off = 1; off <= 8; off <<= 1)
        #pragma unroll
        for (int mi = 0; mi < 4; ++mi)
            #pragma unroll
            for (int r = 0; r < 4; ++r)
                partAcc[mi][r] += __shfl_xor(partAcc[mi][r], off);

    if ((l & 15) == 0) {
        const int rg = (l >> 4) * 4;     // C/D layout: row = (l>>4)*4 + reg
        #pragma unroll
        for (int mi = 0; mi < 4; ++mi)
            #pragma unroll
            for (int r = 0; r < 4; ++r)
                atomicAdd(&rowsum[rowBase + wr * 64 + mi * 16 + rg + r],
                          partAcc[mi][r]);
    }
}

// ---------------------------------------------------------------------------
// Kernel 3: loss = mean_b [ log(exp(pos_b) + rowsum_b) - pos_b ]
// ---------------------------------------------------------------------------
__global__ __launch_bounds__(1024) void finalize_kernel(
    const float* __restrict__ pos_logit, const float* __restrict__ rowsum,
    float* __restrict__ out, int B)
{
    __shared__ float red[1024];
    float acc = 0.f;
    for (int b = (int)threadIdx.x; b < B; b += 1024) {
        const float pl = pos_logit[b];
        acc += logf(expf(pl) + rowsum[b]) - pl;
    }
    red[threadIdx.x] = acc;
    __syncthreads();
    #pragma unroll
    for (int s = 512; s; s >>= 1) {
        if ((int)threadIdx.x < s) red[threadIdx.x] += red[threadIdx.x + s];
        __syncthreads();
    }
    if (threadIdx.x == 0) out[0] = red[0] / (float)B;
}

// ---------------------------------------------------------------------------
extern "C" void kernel_launch(void* const* d_in, const int* in_sizes, int n_in,
                              void* d_out, int out_size, void* d_ws, size_t ws_size,
                              hipStream_t stream)
{
    const float* ei = (const float*)d_in[0];
    const float* ej = (const float*)d_in[1];
    const float* ek = (const float*)d_in[2];
    const int B = in_sizes[0] / D_DIM;   // 8192

    unsigned short* zi = (unsigned short*)d_ws;
    unsigned short* zk = zi + (size_t)B * D_DIM;
    float* rowsum      = (float*)(zk + (size_t)B * D_DIM);
    float* pos_logit   = rowsum + B;

    prep_kernel<<<dim3((B + 3) / 4), dim3(256), 0, stream>>>(
        ei, ej, ek, zi, zk, pos_logit, rowsum, B);

    dim3 grid(B / (NT * BN), B / BM);    // (8, 64) = 512 blocks = 2/CU
    sim_mfma_kernel<<<grid, dim3(256), 0, stream>>>(zi, zk, rowsum);

    finalize_kernel<<<dim3(1), dim3(1024), 0, stream>>>(
        pos_logit, rowsum, (float*)d_out, B);
}